// Round 5
// baseline (474.678 us; speedup 1.0000x reference)
//
#include <hip/hip_runtime.h>

// Model dims (fixed by the problem)
#define TT    128
#define CC    64
#define HH    4
#define SS    16
#define D4    256     // 4*C
#define HID_  256
#define VV    32000
#define NPE_  4
#define RR    256     // B*T
#define NBLK  256     // persistent-kernel grid

__device__ __forceinline__ float wred_sum(float v) {
#pragma unroll
    for (int off = 32; off; off >>= 1) v += __shfl_xor(v, off, 64);
    return v;
}
__device__ __forceinline__ float wred_max(float v) {
#pragma unroll
    for (int off = 32; off; off >>= 1) v = fmaxf(v, __shfl_xor(v, off, 64));
    return v;
}
__device__ __forceinline__ float sigm(float x) { return 1.f / (1.f + __expf(-x)); }

// grid barrier: one arrival counter per slot (64B apart), device-scope atomics
__device__ __forceinline__ void gbar(unsigned* bar, int slot) {
    __syncthreads();
    if (threadIdx.x == 0) {
        __threadfence();
        unsigned* c = bar + slot * 16;
        atomicAdd(c, 1u);
        while (__hip_atomic_load(c, __ATOMIC_RELAXED, __HIP_MEMORY_SCOPE_AGENT) < NBLK)
            __builtin_amdgcn_s_sleep(8);
        __threadfence();
    }
    __syncthreads();
}

// =================== persistent body kernel ===================
__global__ void __launch_bounds__(256, 2) k_body(
    const int* __restrict__ idx, const float* __restrict__ tok,
    const float* __restrict__ pe_tab, const float* __restrict__ peW1,
    const float* __restrict__ peb1, const float* __restrict__ peW2,
    const float* __restrict__ peb2, const float* __restrict__ peg,
    const float* __restrict__ pebb,
    const float* __restrict__ ln1g, const float* __restrict__ ln1b,
    const float* __restrict__ attW1, const float* __restrict__ ab1,
    const float* __restrict__ aw2, const float* __restrict__ ab2,
    const float* __restrict__ valW,
    const float* __restrict__ projW, const float* __restrict__ projb,
    const float* __restrict__ g2, const float* __restrict__ b2,
    const float* __restrict__ fW1, const float* __restrict__ fb1,
    const float* __restrict__ fW2, const float* __restrict__ fb2,
    const float* __restrict__ g3, const float* __restrict__ b3,
    float* __restrict__ x, float* __restrict__ pos, float* __restrict__ v,
    float* __restrict__ Kp, float* __restrict__ Qp, unsigned* __restrict__ bar) {

    const int b = blockIdx.x, tid = threadIdx.x;
    const int lane = tid & 63, wv = tid >> 6;

    __shared__ float pp_pe[2][CC], pp_h[2][CC];          // phase 0
    __shared__ float x1[8][128], sxv[CC];                // phase A
    __shared__ __align__(16) float q_s[HH][D4];          // phase B
    __shared__ __align__(16) float w2_s[HH][D4];
    __shared__ float sc[HH][TT];
    __shared__ float part[HH][4][SS];
    __shared__ float o_s[CC], s_x[CC], s_h[HID_], red[4][CC];

    // ---------------- phase 0: embed + positional embeddings ----------------
    if (wv < 2) {
        int task = b * 2 + wv, p = task >> 7, t = task & 127, c = lane;
        pp_pe[wv][c] = pe_tab[(p * TT + t) * CC + c];
        const float* w1 = peW1 + p * CC * CC;
        float a = peb1[p * CC + c];
        for (int k = 0; k < CC; k++) a += pp_pe[wv][k] * w1[k * CC + c];
        pp_h[wv][c] = sigm(a);
        const float* w2 = peW2 + p * CC * CC;
        float o = peb2[p * CC + c];
        for (int k = 0; k < CC; k++) o += pp_h[wv][k] * w2[k * CC + c];
        float m = wred_sum(o) * (1.f / CC);
        float d = o - m;
        float var = wred_sum(d * d) * (1.f / CC);
        pos[(p * TT + t) * CC + c] =
            d * rsqrtf(var + 1e-5f) * peg[p * CC + c] + pebb[p * CC + c];
    } else if (wv == 2) {
        x[b * CC + lane] = tok[idx[b] * CC + lane];
    }
    gbar(bar, 0);

    for (int p = 0; p < NPE_; ++p) {
        const float* pos_p = pos + p * TT * CC;
        // ---------------- phase A: LN1 + KQ proj + V proj ----------------
        {
            int rg = b & 31, kq = (b >> 5) & 1, h = b >> 6;
            int r0 = rg * 8;
#pragma unroll
            for (int pass = 0; pass < 2; ++pass) {
                int rr = wv + pass * 4;
                float xv = x[(r0 + rr) * CC + lane];
                float m = wred_sum(xv) * (1.f / CC);
                float d = xv - m;
                float var = wred_sum(d * d) * (1.f / CC);
                x1[rr][64 + lane] = d * rsqrtf(var + 1e-5f) * ln1g[lane] + ln1b[lane];
            }
            for (int e = tid; e < 512; e += 256) {
                int rr = e >> 6, cc = e & 63;
                int t = (r0 + rr) & (TT - 1);
                x1[rr][cc] = pos_p[t * CC + cc];
            }
            __syncthreads();
            const float* w = attW1 + (h * D4 + kq * 128) * D4;
            float acc[8] = {0, 0, 0, 0, 0, 0, 0, 0};
            for (int c = 0; c < 128; c++) {
                float wvv = w[c * D4 + tid];
#pragma unroll
                for (int rr = 0; rr < 8; rr++) acc[rr] += x1[rr][c] * wvv;
            }
            // fold att_b1 into K so scores = sigm(q + k')
            float badd = kq ? 0.f : ab1[h * D4 + tid];
            float* out = kq ? Qp : Kp;
#pragma unroll
            for (int rr = 0; rr < 8; rr++)
                out[(h * RR + r0 + rr) * D4 + tid] = acc[rr] + badd;
            // V projection for row b
            __syncthreads();
            if (wv == 0) {
                float xv = x[b * CC + lane];
                float m = wred_sum(xv) * (1.f / CC);
                float d = xv - m;
                float var = wred_sum(d * d) * (1.f / CC);
                sxv[lane] = d * rsqrtf(var + 1e-5f) * ln1g[lane] + ln1b[lane];
            }
            __syncthreads();
            if (wv == 1) {
                int hh = lane >> 4, sd = lane & 15;
                const float* wvw = valW + hh * CC * SS;
                float a = 0.f;
                for (int k = 0; k < CC; k++) a += sxv[k] * wvw[k * SS + sd];
                v[(hh * RR + b) * SS + sd] = a;
            }
        }
        gbar(bar, 1 + p * 2);

        // ---------------- phase B: attention + proj/FF/LNs (row = b) ----------
        {
            int row = b, bb_ = row >> 7, i = row & 127;
            int h = wv;
            for (int e = tid; e < HH * D4; e += 256) {
                int hh = e >> 8, d = e & 255;
                q_s[hh][d] = Qp[(hh * RR + row) * D4 + d];
                w2_s[hh][d] = aw2[hh * D4 + d] * 0.125f;   // fold C^-0.5
            }
            __syncthreads();
            // scores, transposed: lane = j, serial over d (no cross-lane reduce)
            const float* Kb = Kp + (h * RR + bb_ * TT) * D4;
            float b2s = ab2[h] * 0.125f;
#pragma unroll
            for (int jp = 0; jp < 2; ++jp) {
                int j = jp * 64 + lane;
                if (j <= i) {
                    const float* kj = Kb + j * D4;
                    float a = 0.f;
#pragma unroll 4
                    for (int d = 0; d < D4; d += 4) {
                        float4 kk = *(const float4*)(kj + d);
                        float4 q4 = *(const float4*)&q_s[h][d];
                        float4 w4 = *(const float4*)&w2_s[h][d];
                        a += sigm(q4.x + kk.x) * w4.x + sigm(q4.y + kk.y) * w4.y +
                             sigm(q4.z + kk.z) * w4.z + sigm(q4.w + kk.w) * w4.w;
                    }
                    sc[h][j] = a + b2s;
                }
            }
            // softmax per head (wave h)
            {
                float s0 = (lane <= i) ? sc[h][lane] : -1e30f;
                float s1 = (lane + 64 <= i) ? sc[h][lane + 64] : -1e30f;
                float m = wred_max(fmaxf(s0, s1));
                float e0 = (lane <= i) ? __expf(s0 - m) : 0.f;
                float e1 = (lane + 64 <= i) ? __expf(s1 - m) : 0.f;
                float inv = 1.f / wred_sum(e0 + e1);
                sc[h][lane] = e0 * inv;
                sc[h][lane + 64] = e1 * inv;
            }
            // PV
            {
                int jg = lane >> 4, s = lane & 15;
                const float* vb = v + (h * RR + bb_ * TT) * SS;
                float acc = 0.f;
                for (int j = jg; j <= i; j += 4) acc += sc[h][j] * vb[j * SS + s];
                part[h][jg][s] = acc;
            }
            __syncthreads();
            if (tid < CC) {
                int hh = tid >> 4, s = tid & 15;
                o_s[tid] = part[hh][0][s] + part[hh][1][s] + part[hh][2][s] + part[hh][3][s];
            }
            __syncthreads();
            float xv = 0.f;
            if (tid < CC) {
                float acc = projb[tid];
                for (int k = 0; k < CC; k++) acc += o_s[k] * projW[k * CC + tid];
                xv = x[row * CC + tid] + acc;
                float m = wred_sum(xv) * (1.f / CC);
                float d = xv - m;
                float var = wred_sum(d * d) * (1.f / CC);
                s_x[tid] = d * rsqrtf(var + 1e-5f) * g2[tid] + b2[tid];
            }
            __syncthreads();
            {
                float a = fb1[tid];
                for (int k = 0; k < CC; k++) a += s_x[k] * fW1[k * HID_ + tid];
                s_h[tid] = sigm(a);
            }
            __syncthreads();
            {
                int c = tid & 63, q = tid >> 6;
                float acc = 0.f;
                for (int k = q * 64; k < q * 64 + 64; ++k) acc += s_h[k] * fW2[k * CC + c];
                red[q][c] = acc;
            }
            __syncthreads();
            if (tid < CC) {
                float f = fb2[tid] + red[0][tid] + red[1][tid] + red[2][tid] + red[3][tid];
                float x2 = xv + f;
                float m = wred_sum(x2) * (1.f / CC);
                float d = x2 - m;
                float var = wred_sum(d * d) * (1.f / CC);
                x[row * CC + tid] = d * rsqrtf(var + 1e-5f) * g3[tid] + b3[tid];
            }
        }
        if (p < NPE_ - 1) gbar(bar, 2 + p * 2);
    }
}

// =================== lm_head: c-outer register GEMM ===================
// grid (125, 4); block = 256 cols x 64 rows; thread = 2 cols x 32 rows
__global__ void __launch_bounds__(256, 4) k_lmhead(const float* __restrict__ x,
                                                   const float* __restrict__ lmW,
                                                   const float* __restrict__ lmb,
                                                   float* __restrict__ out) {
    int tid = threadIdx.x;
    int cp = tid & 127, rg = tid >> 7;
    int v2 = blockIdx.x * 256 + cp * 2;
    int r0 = blockIdx.y * 64;
    int rbase = rg * 32;
    __shared__ float xT[CC][68];            // transposed x tile, padded
    for (int e = tid; e < 64 * CC; e += 256) {
        int r = e >> 6, c = e & 63;
        xT[c][r] = x[(r0 + r) * CC + c];
    }
    __syncthreads();
    float2 bias = *(const float2*)(lmb + v2);
    float2 acc[32];
#pragma unroll
    for (int rr = 0; rr < 32; rr++) acc[rr] = bias;
    for (int c = 0; c < CC; ++c) {
        float2 w = *(const float2*)(lmW + (size_t)c * VV + v2);
#pragma unroll
        for (int q = 0; q < 8; ++q) {
            float4 xr = *(const float4*)&xT[c][rbase + q * 4];
            acc[q * 4 + 0].x += xr.x * w.x; acc[q * 4 + 0].y += xr.x * w.y;
            acc[q * 4 + 1].x += xr.y * w.x; acc[q * 4 + 1].y += xr.y * w.y;
            acc[q * 4 + 2].x += xr.z * w.x; acc[q * 4 + 2].y += xr.z * w.y;
            acc[q * 4 + 3].x += xr.w * w.x; acc[q * 4 + 3].y += xr.w * w.y;
        }
    }
#pragma unroll
    for (int rr = 0; rr < 32; rr++)
        *(float2*)(out + (size_t)(r0 + rbase + rr) * VV + v2) = acc[rr];
}

extern "C" void kernel_launch(void* const* d_in, const int* in_sizes, int n_in,
                              void* d_out, int out_size, void* d_ws, size_t ws_size,
                              hipStream_t stream) {
    const int*   idx   = (const int*)d_in[0];
    const float* tok   = (const float*)d_in[1];
    const float* petab = (const float*)d_in[2];
    const float* peW1  = (const float*)d_in[3];
    const float* peb1  = (const float*)d_in[4];
    const float* peW2  = (const float*)d_in[5];
    const float* peb2  = (const float*)d_in[6];
    const float* peg   = (const float*)d_in[7];
    const float* pebb  = (const float*)d_in[8];
    const float* ln1g  = (const float*)d_in[9];
    const float* ln1b  = (const float*)d_in[10];
    const float* attW1 = (const float*)d_in[11];
    const float* attb1 = (const float*)d_in[12];
    const float* attW2 = (const float*)d_in[13];
    const float* attb2 = (const float*)d_in[14];
    const float* valW  = (const float*)d_in[15];
    const float* projW = (const float*)d_in[16];
    const float* projb = (const float*)d_in[17];
    const float* ln2g  = (const float*)d_in[18];
    const float* ln2b  = (const float*)d_in[19];
    const float* ffW1  = (const float*)d_in[20];
    const float* ffb1  = (const float*)d_in[21];
    const float* ffW2  = (const float*)d_in[22];
    const float* ffb2  = (const float*)d_in[23];
    const float* ln3g  = (const float*)d_in[24];
    const float* ln3b  = (const float*)d_in[25];
    const float* lmW   = (const float*)d_in[26];
    const float* lmb   = (const float*)d_in[27];

    float* ws  = (float*)d_ws;
    float* x   = ws;                  // 16384
    float* pos = ws + 16384;          // 32768
    float* v   = ws + 49152;          // 16384
    float* Kp  = ws + 65536;          // 262144 (includes +att_b1)
    float* Qp  = ws + 327680;         // 262144
    unsigned* bar = (unsigned*)(ws + 600000);   // 8 slots x 64B

    hipMemsetAsync(bar, 0, 8 * 16 * sizeof(unsigned), stream);
    k_body<<<NBLK, 256, 0, stream>>>(idx, tok, petab, peW1, peb1, peW2, peb2,
                                     peg, pebb, ln1g, ln1b, attW1, attb1, attW2,
                                     attb2, valW, projW, projb, ln2g, ln2b,
                                     ffW1, ffb1, ffW2, ffb2, ln3g, ln3b,
                                     x, pos, v, Kp, Qp, bar);
    k_lmhead<<<dim3(125, 4), 256, 0, stream>>>(x, lmW, lmb, (float*)d_out);
}